// Round 5
// baseline (653.154 us; speedup 1.0000x reference)
//
#include <hip/hip_runtime.h>
#include <hip/hip_bf16.h>

#define Bq   16
#define Nseq 1024
#define Cdim 768
#define NH2  24
#define W2D  1536
#define KB   16
#define NMB  64

typedef short bfrag8 __attribute__((ext_vector_type(8)));   // 8 bf16 (4 VGPRs)
typedef short bfrag4 __attribute__((ext_vector_type(4)));   // 4 bf16 (2 VGPRs)
typedef float f32x4  __attribute__((ext_vector_type(4)));

__device__ __forceinline__ short f2bs(float x) {
  union { __hip_bfloat16 b; short s; } u;
  u.b = __float2bfloat16(x);
  return u.s;
}
__device__ __forceinline__ bfrag8 cvt8(const float* v) {
  bfrag8 r;
#pragma unroll
  for (int i = 0; i < 8; ++i) r[i] = f2bs(v[i]);
  return r;
}
__device__ __forceinline__ bfrag4 cvt4(float a, float b, float c, float d) {
  bfrag4 r;
  r[0] = f2bs(a); r[1] = f2bs(b); r[2] = f2bs(c); r[3] = f2bs(d);
  return r;
}
__device__ __forceinline__ void async_copy16(const void* g, void* l) {
  __builtin_amdgcn_global_load_lds((const __attribute__((address_space(1))) void*)g,
                                   (__attribute__((address_space(3))) void*)l, 16, 0, 0);
}

// K=16 bf16 MFMA (A,B: 4 bf16/lane, k = quad*4+j — matches C-layout row index).
#if defined(__has_builtin)
#  if __has_builtin(__builtin_amdgcn_mfma_f32_16x16x16bf16_1k)
#    define HAVE_MFMA16X16X16 1
#  endif
#endif
__device__ __forceinline__ f32x4 mfma16(bfrag4 a, bfrag4 b, f32x4 c) {
#ifdef HAVE_MFMA16X16X16
  return __builtin_amdgcn_mfma_f32_16x16x16bf16_1k(a, b, c, 0, 0, 0);
#else
  f32x4 d;
  asm volatile("v_mfma_f32_16x16x16_bf16 %0, %1, %2, %3"
               : "=v"(d) : "v"(a), "v"(b), "v"(c));
  return d;
#endif
}

// Intra-wave LDS fence: orders ds_write -> ds_read across lanes of ONE wave.
// lgkmcnt-only (no vmcnt drain => global prefetch stays in flight).
__device__ __forceinline__ void lds_fence() {
  asm volatile("s_waitcnt lgkmcnt(0)" ::: "memory");
  __builtin_amdgcn_sched_barrier(0);
}

// DPP rotate within 16-lane row: full-rate VALU cross-lane (no LDS pipe).
template<int N>
__device__ __forceinline__ float dpp_ror(float x) {
  union { float f; int i; } a, r;
  a.f = x;
  r.i = __builtin_amdgcn_update_dpp(0, a.i, 0x120 | N, 0xF, 0xF, 1);
  return r.f;
}
// all-reduce sum over each 16-lane row (result in every lane of the row)
__device__ __forceinline__ float rowsum16(float x) {
  x += dpp_ror<8>(x);
  x += dpp_ror<4>(x);
  x += dpp_ror<2>(x);
  x += dpp_ror<1>(x);
  return x;
}

// ---------------- bf16 MFMA GEMM: C[M,N] = A[M,K] @ Bt[N,K]^T (+bias) --------
// 1D grid, bijective XCD chunk swizzle (grid % 8 == 0): XCD k processes a
// CONTIGUOUS range of logical tiles, n-fastest => per-XCD working set is
// ~16 A-panels (3.1 MB) + B panel — L2-resident instead of L2-thrashing.
__global__ __launch_bounds__(256) void gemm_bf16_kernel(
    const __hip_bfloat16* __restrict__ A,   // M x K row-major
    const __hip_bfloat16* __restrict__ Bt,  // N x K row-major (B transposed)
    const float* __restrict__ bias, float* __restrict__ C,
    int M, int Kd, int Nd, int gx)          // gx = Nd/128
{
  __shared__ short sA[128 * 64];
  __shared__ short sB[128 * 64];
  const int t = threadIdx.x;
  const int w = t >> 6, lane = t & 63;
  const int quad = lane >> 4, li = lane & 15;
  const int wm = w & 1, wn = w >> 1;

  const int nwg = gridDim.x;
  const int q8 = nwg >> 3;
  const int lid = ((int)blockIdx.x & 7) * q8 + ((int)blockIdx.x >> 3);
  const int m0 = (lid / gx) * 128, n0 = (lid % gx) * 128;

  f32x4 acc[4][4];
#pragma unroll
  for (int mt = 0; mt < 4; ++mt)
#pragma unroll
    for (int nt = 0; nt < 4; ++nt) acc[mt][nt] = (f32x4){0.f, 0.f, 0.f, 0.f};

  const __hip_bfloat16* Ab = A + (size_t)m0 * Kd;
  const __hip_bfloat16* Bb = Bt + (size_t)n0 * Kd;

#pragma unroll 1
  for (int k0 = 0; k0 < Kd; k0 += 64) {
    __syncthreads();
#pragma unroll
    for (int i = 0; i < 4; ++i) {
      int c = i * 256 + t;
      int row = c >> 3;
      int gl = (c & 7) ^ (row & 7);
      async_copy16(Ab + (size_t)row * Kd + k0 + gl * 8, &sA[c * 8]);
      async_copy16(Bb + (size_t)row * Kd + k0 + gl * 8, &sB[c * 8]);
    }
    __syncthreads();
#pragma unroll
    for (int ks = 0; ks < 2; ++ks) {
      bfrag8 aF[4], bF[4];
#pragma unroll
      for (int mt = 0; mt < 4; ++mt) {
        int row = wm * 64 + mt * 16 + li;
        int gi = (ks * 4 + quad) ^ (row & 7);
        aF[mt] = *(const bfrag8*)(&sA[row * 64 + gi * 8]);
      }
#pragma unroll
      for (int nt = 0; nt < 4; ++nt) {
        int row = wn * 64 + nt * 16 + li;
        int gi = (ks * 4 + quad) ^ (row & 7);
        bF[nt] = *(const bfrag8*)(&sB[row * 64 + gi * 8]);
      }
#pragma unroll
      for (int mt = 0; mt < 4; ++mt)
#pragma unroll
        for (int nt = 0; nt < 4; ++nt)
          acc[mt][nt] = __builtin_amdgcn_mfma_f32_16x16x32_bf16(aF[mt], bF[nt], acc[mt][nt], 0, 0, 0);
    }
  }

#pragma unroll
  for (int mt = 0; mt < 4; ++mt)
#pragma unroll
    for (int nt = 0; nt < 4; ++nt) {
      int ncol = n0 + wn * 64 + nt * 16 + li;
      float bv = bias ? bias[ncol] : 0.f;
#pragma unroll
      for (int r = 0; r < 4; ++r) {
        int mrow = m0 + wm * 64 + mt * 16 + quad * 4 + r;
        C[(size_t)mrow * Nd + ncol] = acc[mt][nt][r] + bv;
      }
    }
}

// ---------------- f32 -> bf16 cast (x4 vectorized) ---------------------------
__global__ __launch_bounds__(256) void cast_bf16_kernel(
    const float* __restrict__ in, __hip_bfloat16* __restrict__ out, int n4)
{
  int i = blockIdx.x * 256 + threadIdx.x;
  if (i >= n4) return;
  float4 v = ((const float4*)in)[i];
  union { short b[4]; short4 s; } u;
  u.b[0] = f2bs(v.x); u.b[1] = f2bs(v.y); u.b[2] = f2bs(v.z); u.b[3] = f2bs(v.w);
  ((short4*)out)[i] = u.s;
}

// ---------------- transpose + cast: Bt[n][k] = (bf16)B[k][n] -----------------
__global__ __launch_bounds__(256) void transpose_cast_kernel(
    const float* __restrict__ B, __hip_bfloat16* __restrict__ Bt, int Kd, int Nd)
{
  __shared__ float tl[64][65];
  int k0 = blockIdx.x * 64, n0 = blockIdx.y * 64;
  int tx = threadIdx.x & 63, ty = threadIdx.x >> 6;
#pragma unroll
  for (int i = 0; i < 16; ++i) {
    int k = ty + i * 4;
    tl[k][tx] = B[(size_t)(k0 + k) * Nd + n0 + tx];
  }
  __syncthreads();
#pragma unroll
  for (int i = 0; i < 16; ++i) {
    int n = ty + i * 4;
    Bt[(size_t)(n0 + n) * Kd + k0 + tx] = __float2bfloat16(tl[tx][n]);
  }
}

// ---------------- lr = sigmoid(xx @ lr_w + lr_b) / hd — one wave per row -----
__global__ __launch_bounds__(64) void lr_kernel(
    const float* __restrict__ x, const float* __restrict__ lr_w,
    const float* __restrict__ lr_b, float* __restrict__ lrout)
{
  const int row = blockIdx.x;            // 0..16383
  const int b = row >> 10, n = row & 1023;
  const int l = threadIdx.x;
  const float* x1 = x + (size_t)row * Cdim;
  const float* x2 = x + (size_t)(b * Nseq + (Nseq - 1 - n)) * Cdim;

  float acc[NH2];
#pragma unroll
  for (int hh = 0; hh < NH2; ++hh) acc[hh] = 0.f;

#pragma unroll 1
  for (int i = 0; i < 12; ++i) {
    int c = l + 64 * i;
    float xv1 = x1[c];
    float xv2 = x2[c];
    const float4* w1 = (const float4*)(lr_w + (size_t)c * NH2);
    const float4* w2 = (const float4*)(lr_w + (size_t)(Cdim + c) * NH2);
#pragma unroll
    for (int q4 = 0; q4 < 6; ++q4) {
      float4 wa = w1[q4], wb = w2[q4];
      acc[q4 * 4 + 0] += xv1 * wa.x + xv2 * wb.x;
      acc[q4 * 4 + 1] += xv1 * wa.y + xv2 * wb.y;
      acc[q4 * 4 + 2] += xv1 * wa.z + xv2 * wb.z;
      acc[q4 * 4 + 3] += xv1 * wa.w + xv2 * wb.w;
    }
  }
#pragma unroll
  for (int hh = 0; hh < NH2; ++hh) {
    float s = rowsum16(acc[hh]);
    s += __shfl_xor(s, 16);
    s += __shfl_xor(s, 32);
    acc[hh] = s;
  }
  float mine = 0.f;
#pragma unroll
  for (int hh = 0; hh < NH2; ++hh) mine = (l == hh) ? acc[hh] : mine;
  if (l < NH2) {
    float a = mine + lr_b[l];
    float sg = 1.f / (1.f + expf(-a));
    lrout[(size_t)row * NH2 + l] = sg * (1.f / 64.f);
  }
}

// ---------------- single-wave MFMA TTT scan, all-K16, dbuf staging -----------
// grid 384 x 64 threads (64-thread blocks: proven no-spill config; 512-thread
// blocks cap at 128 VGPR on this toolchain and spill — R2/R3).
// Double-buffered LDS: iter m reads tile m from buf[m&1] IMMEDIATELY (staged
// last iter), then stages tile m+1 into buf[~m&1]; ONE lds_fence per iter at
// the end. Rotary VALU overlaps the frag-read latency. K/V/Q are additionally
// staged TRANSPOSED (stride-20 pad) so all C-layout reads are ds_read_b128.
// W state = 4x4 K16 B-frags; G-MFMA D-layout == W-frag k-layout => register
// W-update. Coef from swapped attn MFMA, in-register. Reductions via DPP.
// Frag contract (mfma_f32_16x16x16_bf16): A[m=li][k=quad*4+j],
// B[n=li][k=quad*4+j], D: col=li, row=quad*4+reg.
__global__ __launch_bounds__(64, 1) void ttt_scan_kernel(
    const float* __restrict__ qkv,   // (B,N,2304)
    const float* __restrict__ lrg,   // (B,N,24)
    const float* __restrict__ W1,    // (24,64,64) [ch_in][ch_out]
    const float* __restrict__ b1g,   // (24,64)
    const float* __restrict__ lnw,   // (24,64)
    const float* __restrict__ lnb,   // (24,64)
    const float* __restrict__ tid,   // (16,)
    float* __restrict__ Zout)        // (B,N,1536)
{
  __shared__ float sQb[2][16 * 68];   // row-major [tok][ch] (A-frags)
  __shared__ float sKb[2][16 * 68];
  __shared__ float sQT[2][64 * 20];   // transposed [ch][tok], stride 20
  __shared__ float sKT[2][64 * 20];
  __shared__ float sVT[2][64 * 20];

  const int l = threadIdx.x;            // 0..63
  const int quad = l >> 4, li = l & 15;
  const int bh = blockIdx.x, b = bh / NH2, h = bh % NH2;
  const int chan = (h < 12) ? h * 64 : (h - 12) * 64;
  const bool flip = (h >= 12);
  const int bN = b * Nseq;
  const int stok = l >> 2, sc0 = (l & 3) * 16;  // staging token / channel base

  // W state: Wf[t][kk][j] = W1[kk*16+quad*4+j][t*16+li]
  float Wf[4][4][4];
  bfrag4 wB[4][4];
#pragma unroll
  for (int t = 0; t < 4; ++t)
#pragma unroll
    for (int kk = 0; kk < 4; ++kk) {
#pragma unroll
      for (int j = 0; j < 4; ++j)
        Wf[t][kk][j] = W1[h * 4096 + (kk * 16 + quad * 4 + j) * 64 + t * 16 + li];
      wB[t][kk] = cvt4(Wf[t][kk][0], Wf[t][kk][1], Wf[t][kk][2], Wf[t][kk][3]);
    }
  float bC[4], gv[4], bt_[4];
#pragma unroll
  for (int t = 0; t < 4; ++t) {
    bC[t]  = b1g[h * 64 + t * 16 + li];
    gv[t]  = lnw[h * 64 + t * 16 + li];
    bt_[t] = lnb[h * 64 + t * 16 + li];
  }

  float tokL;
  {
    float tk = 1.f / (float)(li + 1) + tid[li];
    tokL = tk > 0.f ? tk : 0.f;
  }
  float t15 = 1.f / 16.f + tid[15];
  t15 = t15 > 0.f ? t15 : 0.f;

  // rotary tables: lane stages token stok, channels sc0..sc0+15
  float c8[8], s8[8];
  {
#pragma unroll
    for (int pl = 0; pl < 8; ++pl) {
      int p = (l & 3) * 8 + pl;
      float inv = __expf(-((float)(2 * p) * (1.f / 64.f)) * 9.210340371976184f);
      float a = (float)stok * inv;
      c8[pl] = cosf(a);
      s8[pl] = sinf(a);
    }
  }

  float4 pf[3][4];      // in-flight q,k,v tile
  float lrcur[4], pfl[4];

  // issue global loads for tile mt into pf
  auto issue_qkv = [&](int mt) {
    int nn = mt * KB + stok;
    int grow = flip ? (bN + Nseq - 1 - nn) : (bN + nn);
#pragma unroll
    for (int a = 0; a < 3; ++a) {
      const float* bse = qkv + (size_t)grow * 2304 + chan + a * 768 + sc0;
#pragma unroll
      for (int i = 0; i < 4; ++i) pf[a][i] = ((const float4*)bse)[i];
    }
  };
  // stage pf into buffer buf (rotary on q,k; row-major Q,K; transposed Q,K,V)
  auto stage = [&](int buf) {
#pragma unroll
    for (int a = 0; a < 3; ++a) {
      float v16[16];
      *(float4*)(v16)      = pf[a][0]; *(float4*)(v16 + 4)  = pf[a][1];
      *(float4*)(v16 + 8)  = pf[a][2]; *(float4*)(v16 + 12) = pf[a][3];
      if (a < 2) {
#pragma unroll
        for (int pl = 0; pl < 8; ++pl) {
          float e = v16[2 * pl], o = v16[2 * pl + 1];
          v16[2 * pl]     = e * c8[pl] - o * s8[pl];
          v16[2 * pl + 1] = o * c8[pl] + e * s8[pl];
        }
      }
      if (a == 0) {
        float* dst = &sQb[buf][stok * 68 + sc0];
#pragma unroll
        for (int i = 0; i < 4; ++i) ((f32x4*)dst)[i] = *(f32x4*)(v16 + 4 * i);
#pragma unroll
        for (int i = 0; i < 16; ++i) sQT[buf][(sc0 + i) * 20 + stok] = v16[i];
      } else if (a == 1) {
        float* dst = &sKb[buf][stok * 68 + sc0];
#pragma unroll
        for (int i = 0; i < 4; ++i) ((f32x4*)dst)[i] = *(f32x4*)(v16 + 4 * i);
#pragma unroll
        for (int i = 0; i < 16; ++i) sKT[buf][(sc0 + i) * 20 + stok] = v16[i];
      } else {
#pragma unroll
        for (int i = 0; i < 16; ++i) sVT[buf][(sc0 + i) * 20 + stok] = v16[i];
      }
    }
  };

  // prologue: tile 0 -> buf 0; prefetch tile 1; lr for tiles 0,1
  issue_qkv(0);
#pragma unroll
  for (int r = 0; r < 4; ++r) lrcur[r] = lrg[(size_t)(bN + quad * 4 + r) * NH2 + h];
  stage(0);
  issue_qkv(1);
#pragma unroll
  for (int r = 0; r < 4; ++r) pfl[r] = lrg[(size_t)(bN + KB + quad * 4 + r) * NH2 + h];
  lds_fence();

#pragma unroll 1
  for (int m = 0; m < NMB; ++m) {
    const int n0 = m * KB;
    const int cur = m & 1, alt = cur ^ 1;

    // ---- frag + early C-layout reads from cur ----
    f32x4 q4[4], k4[4];
#pragma unroll
    for (int kk = 0; kk < 4; ++kk) {
      k4[kk] = *(const f32x4*)(&sKb[cur][li * 68 + kk * 16 + quad * 4]);
      q4[kk] = *(const f32x4*)(&sQb[cur][li * 68 + kk * 16 + quad * 4]);
    }
    f32x4 kC[4], vC[4];
#pragma unroll
    for (int t = 0; t < 4; ++t) {
      kC[t] = *(const f32x4*)(&sKT[cur][(t * 16 + li) * 20 + quad * 4]);
      vC[t] = *(const f32x4*)(&sVT[cur][(t * 16 + li) * 20 + quad * 4]);
    }
    float lr4[4];
#pragma unroll
    for (int r = 0; r < 4; ++r) lr4[r] = lrcur[r];

    // ---- stage next tile into alt; rotate lr; issue prefetch m+2 ----
    if (m < NMB - 1) {
      stage(alt);
#pragma unroll
      for (int r = 0; r < 4; ++r) lrcur[r] = pfl[r];
      if (m < NMB - 2) {
        issue_qkv(m + 2);
#pragma unroll
        for (int r = 0; r < 4; ++r)
          pfl[r] = lrg[(size_t)(bN + (m + 2) * KB + quad * 4 + r) * NH2 + h];
      }
    }

    // ---- bf16 frags ----
    bfrag4 aQ4[4], aK4[4];
#pragma unroll
    for (int kk = 0; kk < 4; ++kk) {
      aK4[kk] = cvt4(k4[kk][0], k4[kk][1], k4[kk][2], k4[kk][3]);
      aQ4[kk] = cvt4(q4[kk][0], q4[kk][1], q4[kk][2], q4[kk][3]);
    }

    // ---- MFMA: Z1 (16), xqW (16), attn^T (4) ----
    f32x4 accZ[4], accQ[4];
#pragma unroll
    for (int t = 0; t < 4; ++t) {
      accZ[t] = (f32x4){0.f, 0.f, 0.f, 0.f};
      accQ[t] = (f32x4){0.f, 0.f, 0.f, 0.f};
#pragma unroll
      for (int kk = 0; kk < 4; ++kk) {
        accZ[t] = mfma16(aK4[kk], wB[t][kk], accZ[t]);
        accQ[t] = mfma16(aQ4[kk], wB[t][kk], accQ[t]);
      }
    }
    f32x4 accAT = (f32x4){0.f, 0.f, 0.f, 0.f};
#pragma unroll
    for (int kk = 0; kk < 4; ++kk)
      accAT = mfma16(aK4[kk], aQ4[kk], accAT);    // lane: attn[li][quad*4+r]

    // ---- coef A-frag fully in-register ----
    bfrag4 aCoef;
    {
      float cf[4];
#pragma unroll
      for (int r = 0; r < 4; ++r) {
        int j = quad * 4 + r;
        cf[r] = (j <= li) ? (-tokL * (accAT[r] + 1.f)) : 0.f;
      }
      aCoef = cvt4(cf[0], cf[1], cf[2], cf[3]);
    }

    // ---- LN-L2 backward: reductions via DPP (pure VALU) ----
    float gs[4][4];
#pragma unroll
    for (int r = 0; r < 4; ++r) {
      float zt[4], xht[4], gxht[4];
      float s1 = 0.f, s2 = 0.f;
#pragma unroll
      for (int t = 0; t < 4; ++t) {
        zt[t] = accZ[t][r] + bC[t];
        s1 += zt[t];
        s2 += zt[t] * zt[t];
      }
      s1 = rowsum16(s1);
      s2 = rowsum16(s2);
      float mu = s1 * 0.015625f;
      float var = s2 * 0.015625f - mu * mu;
      float rstd = rsqrtf(var + 1e-6f);
      float r1 = 0.f, r2 = 0.f;
#pragma unroll
      for (int t = 0; t < 4; ++t) {
        xht[t] = (zt[t] - mu) * rstd;
        float gout = gv[t] * xht[t] + bt_[t] - (vC[t][r] - kC[t][r]);
        gxht[t] = gout * gv[t];
        r1 += gxht[t];
        r2 += gxht[t] * xht[t];
      }
      r1 = rowsum16(r1);
      r2 = rowsum16(r2);
      float lrr = lr4[r];
#pragma unroll
      for (int t = 0; t < 4; ++t) {
        float gd = (64.f * gxht[t] - r1 - xht[t] * r2) * rstd * 0.015625f;
        gs[t][r] = lrr * gd;
      }
    }

    // ---- K16 frags straight from registers ----
    bfrag4 bGrad[4], aXk[4];
#pragma unroll
    for (int t = 0; t < 4; ++t) {
      bGrad[t] = cvt4(gs[t][0], gs[t][1], gs[t][2], gs[t][3]);
      aXk[t]   = cvt4(kC[t][0], kC[t][1], kC[t][2], kC[t][3]);
    }

    // ---- Z1_bar = xqW + bC_old + coef@gradS ----
    f32x4 zb[4];
#pragma unroll
    for (int t = 0; t < 4; ++t) {
      f32x4 acc = accQ[t];
#pragma unroll
      for (int r = 0; r < 4; ++r) acc[r] += bC[t];
      zb[t] = mfma16(aCoef, bGrad[t], acc);
    }

    // ---- b update EARLY (old bC already consumed by zb); swizzles hide under
    //      the out-LN + G sections ----
#pragma unroll
    for (int t = 0; t < 4; ++t) {
      float g0 = gs[t][0] + gs[t][1] + gs[t][2] + gs[t][3];
      g0 += __shfl_xor(g0, 16);
      g0 += __shfl_xor(g0, 32);
      bC[t] -= t15 * g0;
    }

    // ---- out LN + store (qC via transposed b128 reads) ----
    f32x4 qC[4];
#pragma unroll
    for (int t = 0; t < 4; ++t)
      qC[t] = *(const f32x4*)(&sQT[cur][(t * 16 + li) * 20 + quad * 4]);
#pragma unroll
    for (int r = 0; r < 4; ++r) {
      float s1 = 0.f, s2 = 0.f;
#pragma unroll
      for (int t = 0; t < 4; ++t) { s1 += zb[t][r]; s2 += zb[t][r] * zb[t][r]; }
      s1 = rowsum16(s1);
      s2 = rowsum16(s2);
      float mu = s1 * 0.015625f;
      float var = s2 * 0.015625f - mu * mu;
      float rstd = rsqrtf(var + 1e-6f);
#pragma unroll
      for (int t = 0; t < 4; ++t) {
        float outv = qC[t][r] + gv[t] * (zb[t][r] - mu) * rstd + bt_[t];
        Zout[(size_t)(bN + n0 + quad * 4 + r) * W2D + h * 64 + t * 16 + li] = outv;
      }
    }

    // ---- G = xk^T @ gradS ; W update — PURE REGISTER ----
#pragma unroll
    for (int mt = 0; mt < 4; ++mt)
#pragma unroll
      for (int t = 0; t < 4; ++t) {
        f32x4 g = mfma16(aXk[mt], bGrad[t], (f32x4){0.f, 0.f, 0.f, 0.f});
#pragma unroll
        for (int r = 0; r < 4; ++r) Wf[t][mt][r] -= t15 * g[r];
        wB[t][mt] = cvt4(Wf[t][mt][0], Wf[t][mt][1], Wf[t][mt][2], Wf[t][mt][3]);
      }

    lds_fence();   // staging writes to alt complete; cur reads long done
  }
}

// ---------------- fused post-LN + flip-multiply -> bf16 h --------------------
__global__ __launch_bounds__(256) void postln_mult_kernel(
    const float* __restrict__ Z, const float* __restrict__ wv,
    const float* __restrict__ bb, __hip_bfloat16* __restrict__ hbuf)
{
  __shared__ float red[16];
  const int pair = blockIdx.x;          // 0..8191
  const int b = pair >> 9, n = pair & 511;
  const size_t r1 = (size_t)b * Nseq + n;
  const size_t r2 = (size_t)b * Nseq + (Nseq - 1 - n);
  const float* z1 = Z + r1 * W2D;
  const float* z2 = Z + r2 * W2D;
  const int t = threadIdx.x;

  float v1[6], v2[6];
  float s1a = 0.f, s2a = 0.f, s1b = 0.f, s2b = 0.f;
#pragma unroll
  for (int r = 0; r < 6; ++r) {
    int c = t + 256 * r;
    float a = z1[c]; v1[r] = a; s1a += a; s2a += a * a;
    float d = z2[c]; v2[r] = d; s1b += d; s2b += d * d;
  }
#pragma unroll
  for (int o = 1; o < 64; o <<= 1) {
    s1a += __shfl_xor(s1a, o); s2a += __shfl_xor(s2a, o);
    s1b += __shfl_xor(s1b, o); s2b += __shfl_xor(s2b, o);
  }
  if ((t & 63) == 0) {
    int w = t >> 6;
    red[w] = s1a; red[4 + w] = s2a; red[8 + w] = s1b; red[12 + w] = s2b;
  }
  __syncthreads();
  s1a = red[0] + red[1] + red[2] + red[3];
  s2a = red[4] + red[5] + red[6] + red[7];
  s1b = red[8] + red[9] + red[10] + red[11];
  s2b = red[12] + red[13] + red[14] + red[15];
  float mu1 = s1a * (1.f / 1536.f);
  float var1 = s2a * (1.f / 1536.f) - mu1 * mu1;
  float rstd1 = rsqrtf(var1 + 1e-6f);
  float mu2 = s1b * (1.f / 1536.f);
  float var2 = s2b * (1.f / 1536.f) - mu2 * mu2;
  float rstd2 = rsqrtf(var2 + 1e-6f);
#pragma unroll
  for (int r = 0; r < 3; ++r) {
    int c = t + 256 * r;
    float a1  = wv[c] * (v1[r] - mu1) * rstd1 + bb[c];
    float a1b = wv[c + 768] * (v1[r + 3] - mu1) * rstd1 + bb[c + 768];
    float a2  = wv[c] * (v2[r] - mu2) * rstd2 + bb[c];
    float a2b = wv[c + 768] * (v2[r + 3] - mu2) * rstd2 + bb[c + 768];
    union { __hip_bfloat16 h; short s; } u1, u2;
    u1.h = __float2bfloat16(a1 * a2b);
    u2.h = __float2bfloat16(a2 * a1b);
    ((short*)hbuf)[r1 * Cdim + c] = u1.s;
    ((short*)hbuf)[r2 * Cdim + c] = u2.s;
  }
}

// ---------------- launch -----------------------------------------------------
extern "C" void kernel_launch(void* const* d_in, const int* in_sizes, int n_in,
                              void* d_out, int out_size, void* d_ws, size_t ws_size,
                              hipStream_t stream)
{
  const float* x         = (const float*)d_in[0];
  const float* qkv_w     = (const float*)d_in[1];
  const float* proj_w    = (const float*)d_in[2];
  const float* proj_b    = (const float*)d_in[3];
  const float* W1        = (const float*)d_in[4];
  const float* b1        = (const float*)d_in[5];
  const float* ttt_ln_w  = (const float*)d_in[6];
  const float* ttt_ln_b  = (const float*)d_in[7];
  const float* post_ln_w = (const float*)d_in[8];
  const float* post_ln_b = (const float*)d_in[9];
  const float* lr_w      = (const float*)d_in[10];
  const float* lr_b      = (const float*)d_in[11];
  const float* tid       = (const float*)d_in[12];
  float* out = (float*)d_out;
  float* ws  = (float*)d_ws;

  float* qkv   = ws;                                   // [0, 37748736)
  float* lrbuf = ws + 37748736;                        // [.., 38141952)
  float* Zbuf  = ws + 38141952;                        // [.., 63307776)
  __hip_bfloat16* xbf    = (__hip_bfloat16*)(ws + 38141952);  // dead before Zbuf use
  __hip_bfloat16* wqkv_t = (__hip_bfloat16*)(ws + 44433408);  // dead before Zbuf use
  __hip_bfloat16* hbf    = (__hip_bfloat16*)(ws + 25165824);  // in dead qkv region
  __hip_bfloat16* wproj_t= (__hip_bfloat16*)(ws + 37748736);  // in dead lrbuf region

  const int Mrows = Bq * Nseq;             // 16384

  cast_bf16_kernel<<<(Mrows * Cdim / 4 + 255) / 256, 256, 0, stream>>>(x, xbf, Mrows * Cdim / 4);
  {
    dim3 g(Cdim / 64, 3 * Cdim / 64);
    transpose_cast_kernel<<<g, 256, 0, stream>>>(qkv_w, wqkv_t, Cdim, 3 * Cdim);
  }
  {
    int gx = 3 * Cdim / 128;               // 18
    int nwg = gx * (Mrows / 128);          // 2304 (% 8 == 0)
    gemm_bf16_kernel<<<nwg, 256, 0, stream>>>(xbf, wqkv_t, nullptr, qkv, Mrows, Cdim, 3 * Cdim, gx);
  }
  lr_kernel<<<Mrows, 64, 0, stream>>>(x, lr_w, lr_b, lrbuf);

  ttt_scan_kernel<<<Bq * NH2, 64, 0, stream>>>(qkv, lrbuf, W1, b1, ttt_ln_w, ttt_ln_b, tid, Zbuf);

  postln_mult_kernel<<<Bq * Nseq / 2, 256, 0, stream>>>(Zbuf, post_ln_w, post_ln_b, hbf);
  {
    dim3 g(Cdim / 64, Cdim / 64);
    transpose_cast_kernel<<<g, 256, 0, stream>>>(proj_w, wproj_t, Cdim, Cdim);
  }
  {
    int gx = Cdim / 128;                   // 6
    int nwg = gx * (Mrows / 128);          // 768 (% 8 == 0)
    gemm_bf16_kernel<<<nwg, 256, 0, stream>>>(hbf, wproj_t, proj_b, out, Mrows, Cdim, Cdim, gx);
  }
}

// Round 6
// 520.712 us; speedup vs baseline: 1.2543x; 1.2543x over previous
//
#include <hip/hip_runtime.h>
#include <hip/hip_bf16.h>

#define Bq   16
#define Nseq 1024
#define Cdim 768
#define NH2  24
#define W2D  1536
#define KB   16
#define NMB  64

typedef short bfrag8 __attribute__((ext_vector_type(8)));   // 8 bf16 (4 VGPRs)
typedef short bfrag4 __attribute__((ext_vector_type(4)));   // 4 bf16 (2 VGPRs)
typedef float f32x4  __attribute__((ext_vector_type(4)));

__device__ __forceinline__ short f2bs(float x) {
  union { __hip_bfloat16 b; short s; } u;
  u.b = __float2bfloat16(x);
  return u.s;
}
__device__ __forceinline__ bfrag8 cvt8(const float* v) {
  bfrag8 r;
#pragma unroll
  for (int i = 0; i < 8; ++i) r[i] = f2bs(v[i]);
  return r;
}
__device__ __forceinline__ bfrag4 cvt4(float a, float b, float c, float d) {
  bfrag4 r;
  r[0] = f2bs(a); r[1] = f2bs(b); r[2] = f2bs(c); r[3] = f2bs(d);
  return r;
}
__device__ __forceinline__ void async_copy16(const void* g, void* l) {
  __builtin_amdgcn_global_load_lds((const __attribute__((address_space(1))) void*)g,
                                   (__attribute__((address_space(3))) void*)l, 16, 0, 0);
}

// K=16 bf16 MFMA (A,B: 4 bf16/lane, k = quad*4+j — matches C-layout row index).
#if defined(__has_builtin)
#  if __has_builtin(__builtin_amdgcn_mfma_f32_16x16x16bf16_1k)
#    define HAVE_MFMA16X16X16 1
#  endif
#endif
__device__ __forceinline__ f32x4 mfma16(bfrag4 a, bfrag4 b, f32x4 c) {
#ifdef HAVE_MFMA16X16X16
  return __builtin_amdgcn_mfma_f32_16x16x16bf16_1k(a, b, c, 0, 0, 0);
#else
  f32x4 d;
  asm volatile("v_mfma_f32_16x16x16_bf16 %0, %1, %2, %3"
               : "=v"(d) : "v"(a), "v"(b), "v"(c));
  return d;
#endif
}

// Intra-wave LDS fence: orders ds_write -> ds_read across lanes of ONE wave.
// lgkmcnt-only (no vmcnt drain => global prefetch stays in flight).
__device__ __forceinline__ void lds_fence() {
  asm volatile("s_waitcnt lgkmcnt(0)" ::: "memory");
  __builtin_amdgcn_sched_barrier(0);
}

// DPP rotate within 16-lane row: full-rate VALU cross-lane (no LDS pipe).
template<int N>
__device__ __forceinline__ float dpp_ror(float x) {
  union { float f; int i; } a, r;
  a.f = x;
  r.i = __builtin_amdgcn_update_dpp(0, a.i, 0x120 | N, 0xF, 0xF, 1);
  return r.f;
}
// all-reduce sum over each 16-lane row (result in every lane of the row)
__device__ __forceinline__ float rowsum16(float x) {
  x += dpp_ror<8>(x);
  x += dpp_ror<4>(x);
  x += dpp_ror<2>(x);
  x += dpp_ror<1>(x);
  return x;
}

// ---------------- bf16 MFMA GEMM: C[M,N] = A[M,K] @ Bt[N,K]^T (+bias) --------
// 1D grid, bijective XCD chunk swizzle (grid % 8 == 0). Epilogue bounces each
// wave's 64x64 C-subtile through private LDS so stores are contiguous
// dwordx4 (full-line write coalescing) instead of 4-row-strided scalars.
__global__ __launch_bounds__(256) void gemm_bf16_kernel(
    const __hip_bfloat16* __restrict__ A,   // M x K row-major
    const __hip_bfloat16* __restrict__ Bt,  // N x K row-major (B transposed)
    const float* __restrict__ bias, float* __restrict__ C,
    int M, int Kd, int Nd, int gx)          // gx = Nd/128
{
  __shared__ short sA[128 * 64];
  __shared__ short sB[128 * 64];
  __shared__ float sEp[4][16 * 68];         // per-wave epilogue bounce
  const int t = threadIdx.x;
  const int w = t >> 6, lane = t & 63;
  const int quad = lane >> 4, li = lane & 15;
  const int wm = w & 1, wn = w >> 1;

  const int nwg = gridDim.x;
  const int q8 = nwg >> 3;
  const int lid = ((int)blockIdx.x & 7) * q8 + ((int)blockIdx.x >> 3);
  const int m0 = (lid / gx) * 128, n0 = (lid % gx) * 128;

  f32x4 acc[4][4];
#pragma unroll
  for (int mt = 0; mt < 4; ++mt)
#pragma unroll
    for (int nt = 0; nt < 4; ++nt) acc[mt][nt] = (f32x4){0.f, 0.f, 0.f, 0.f};

  const __hip_bfloat16* Ab = A + (size_t)m0 * Kd;
  const __hip_bfloat16* Bb = Bt + (size_t)n0 * Kd;

#pragma unroll 1
  for (int k0 = 0; k0 < Kd; k0 += 64) {
    __syncthreads();
#pragma unroll
    for (int i = 0; i < 4; ++i) {
      int c = i * 256 + t;
      int row = c >> 3;
      int gl = (c & 7) ^ (row & 7);
      async_copy16(Ab + (size_t)row * Kd + k0 + gl * 8, &sA[c * 8]);
      async_copy16(Bb + (size_t)row * Kd + k0 + gl * 8, &sB[c * 8]);
    }
    __syncthreads();
#pragma unroll
    for (int ks = 0; ks < 2; ++ks) {
      bfrag8 aF[4], bF[4];
#pragma unroll
      for (int mt = 0; mt < 4; ++mt) {
        int row = wm * 64 + mt * 16 + li;
        int gi = (ks * 4 + quad) ^ (row & 7);
        aF[mt] = *(const bfrag8*)(&sA[row * 64 + gi * 8]);
      }
#pragma unroll
      for (int nt = 0; nt < 4; ++nt) {
        int row = wn * 64 + nt * 16 + li;
        int gi = (ks * 4 + quad) ^ (row & 7);
        bF[nt] = *(const bfrag8*)(&sB[row * 64 + gi * 8]);
      }
#pragma unroll
      for (int mt = 0; mt < 4; ++mt)
#pragma unroll
        for (int nt = 0; nt < 4; ++nt)
          acc[mt][nt] = __builtin_amdgcn_mfma_f32_16x16x32_bf16(aF[mt], bF[nt], acc[mt][nt], 0, 0, 0);
    }
  }

  // ---- coalesced epilogue: bounce each 16x64 row-slab through LDS ----
  float* ep = sEp[w];
  const int erow = lane >> 2, ecb = lane & 3;   // read assignment
#pragma unroll
  for (int mt = 0; mt < 4; ++mt) {
#pragma unroll
    for (int nt = 0; nt < 4; ++nt) {
      int ncol = n0 + wn * 64 + nt * 16 + li;
      float bv = bias ? bias[ncol] : 0.f;
#pragma unroll
      for (int r = 0; r < 4; ++r)
        ep[(quad * 4 + r) * 68 + nt * 16 + li] = acc[mt][nt][r] + bv;
    }
    lds_fence();
    {
      size_t rbase = (size_t)(m0 + wm * 64 + mt * 16 + erow) * Nd + n0 + wn * 64 + ecb * 16;
#pragma unroll
      for (int j = 0; j < 4; ++j) {
        f32x4 v = *(const f32x4*)(&ep[erow * 68 + ecb * 16 + 4 * j]);
        *(f32x4*)(&C[rbase + 4 * j]) = v;
      }
    }
    lds_fence();   // drain reads before next mt overwrites ep
  }
}

// ---------------- transpose + cast: Bt[n][k] = (bf16)B[k][n] -----------------
__global__ __launch_bounds__(256) void transpose_cast_kernel(
    const float* __restrict__ B, __hip_bfloat16* __restrict__ Bt, int Kd, int Nd)
{
  __shared__ float tl[64][65];
  int k0 = blockIdx.x * 64, n0 = blockIdx.y * 64;
  int tx = threadIdx.x & 63, ty = threadIdx.x >> 6;
#pragma unroll
  for (int i = 0; i < 16; ++i) {
    int k = ty + i * 4;
    tl[k][tx] = B[(size_t)(k0 + k) * Nd + n0 + tx];
  }
  __syncthreads();
#pragma unroll
  for (int i = 0; i < 16; ++i) {
    int n = ty + i * 4;
    Bt[(size_t)(n0 + n) * Kd + k0 + tx] = __float2bfloat16(tl[tx][n]);
  }
}

// -------- fused: lr for row-pair (n, N-1-n) + bf16 cast of x -----------------
// One wave per pair. Rows n and N-1-n need the SAME two x rows (concat order
// swapped), so load x once, accumulate both heads' dots, and also emit the
// bf16 cast of both rows (replaces the separate cast kernel).
__global__ __launch_bounds__(64) void lrcast_kernel(
    const float* __restrict__ x, const float* __restrict__ lr_w,
    const float* __restrict__ lr_b, float* __restrict__ lrout,
    __hip_bfloat16* __restrict__ xbf)
{
  const int pair = blockIdx.x;           // 0..8191
  const int b = pair >> 9, n = pair & 511;
  const size_t r1 = (size_t)b * Nseq + n;
  const size_t r2 = (size_t)b * Nseq + (Nseq - 1 - n);
  const int l = threadIdx.x;
  const float* x1 = x + r1 * Cdim;
  const float* x2 = x + r2 * Cdim;

  float a1[NH2], a2[NH2];
#pragma unroll
  for (int hh = 0; hh < NH2; ++hh) { a1[hh] = 0.f; a2[hh] = 0.f; }

#pragma unroll 1
  for (int i = 0; i < 12; ++i) {
    int c = l + 64 * i;
    float xv1 = x1[c];
    float xv2 = x2[c];
    ((short*)xbf)[r1 * Cdim + c] = f2bs(xv1);
    ((short*)xbf)[r2 * Cdim + c] = f2bs(xv2);
    const float4* wlo = (const float4*)(lr_w + (size_t)c * NH2);
    const float4* whi = (const float4*)(lr_w + (size_t)(Cdim + c) * NH2);
#pragma unroll
    for (int q4 = 0; q4 < 6; ++q4) {
      float4 wa = wlo[q4], wb = whi[q4];
      a1[q4 * 4 + 0] += xv1 * wa.x + xv2 * wb.x;
      a1[q4 * 4 + 1] += xv1 * wa.y + xv2 * wb.y;
      a1[q4 * 4 + 2] += xv1 * wa.z + xv2 * wb.z;
      a1[q4 * 4 + 3] += xv1 * wa.w + xv2 * wb.w;
      a2[q4 * 4 + 0] += xv2 * wa.x + xv1 * wb.x;
      a2[q4 * 4 + 1] += xv2 * wa.y + xv1 * wb.y;
      a2[q4 * 4 + 2] += xv2 * wa.z + xv1 * wb.z;
      a2[q4 * 4 + 3] += xv2 * wa.w + xv1 * wb.w;
    }
  }
#pragma unroll
  for (int hh = 0; hh < NH2; ++hh) {
    float s = rowsum16(a1[hh]);
    s += __shfl_xor(s, 16);
    s += __shfl_xor(s, 32);
    a1[hh] = s;
    float u = rowsum16(a2[hh]);
    u += __shfl_xor(u, 16);
    u += __shfl_xor(u, 32);
    a2[hh] = u;
  }
  float m1 = 0.f, m2 = 0.f;
#pragma unroll
  for (int hh = 0; hh < NH2; ++hh) {
    m1 = (l == hh) ? a1[hh] : m1;
    m2 = (l == hh) ? a2[hh] : m2;
  }
  if (l < NH2) {
    float v1 = m1 + lr_b[l];
    float v2 = m2 + lr_b[l];
    lrout[r1 * NH2 + l] = (1.f / (1.f + expf(-v1))) * (1.f / 64.f);
    lrout[r2 * NH2 + l] = (1.f / (1.f + expf(-v2))) * (1.f / 64.f);
  }
}

// ---------------- single-wave MFMA TTT scan, all-K16, register W-update ------
// EXACT R4 structure (199 us known-good). grid 384 x 64 threads (64-thread
// blocks: proven no-spill config; 512-thread blocks cap at 128 VGPR and spill
// — R2/R3). R5's transposed staging regressed (write bank conflicts) — keep
// scalar C-layout reads.
// W state = 4x4 K16 B-frags: Wf[t][kk][j] = W[kk*16+quad*4+j][t*16+li].
// G-MFMA D-layout == W-frag k-layout => pure-register W update. Coef from
// swapped attn MFMA, in-register. Reductions via DPP rowsum16.
// Frag contract (mfma_f32_16x16x16_bf16): A[m=li][k=quad*4+j],
// B[n=li][k=quad*4+j], D: col=li, row=quad*4+reg.
__global__ __launch_bounds__(64, 1) void ttt_scan_kernel(
    const float* __restrict__ qkv,   // (B,N,2304)
    const float* __restrict__ lrg,   // (B,N,24)
    const float* __restrict__ W1,    // (24,64,64) [ch_in][ch_out]
    const float* __restrict__ b1g,   // (24,64)
    const float* __restrict__ lnw,   // (24,64)
    const float* __restrict__ lnb,   // (24,64)
    const float* __restrict__ tid,   // (16,)
    float* __restrict__ Zout)        // (B,N,1536)
{
  __shared__ float sQ[16 * 68], sK[16 * 68], sV[16 * 68];  // rotary'd tiles [tok][ch]

  const int l = threadIdx.x;            // 0..63
  const int quad = l >> 4, li = l & 15;
  const int bh = blockIdx.x, b = bh / NH2, h = bh % NH2;
  const int chan = (h < 12) ? h * 64 : (h - 12) * 64;
  const bool flip = (h >= 12);
  const int bN = b * Nseq;

  // W state: Wf[t][kk][j] = W1[kk*16+quad*4+j][t*16+li]
  float Wf[4][4][4];
  bfrag4 wB[4][4];
#pragma unroll
  for (int t = 0; t < 4; ++t)
#pragma unroll
    for (int kk = 0; kk < 4; ++kk) {
#pragma unroll
      for (int j = 0; j < 4; ++j)
        Wf[t][kk][j] = W1[h * 4096 + (kk * 16 + quad * 4 + j) * 64 + t * 16 + li];
      wB[t][kk] = cvt4(Wf[t][kk][0], Wf[t][kk][1], Wf[t][kk][2], Wf[t][kk][3]);
    }
  float bC[4], gv[4], bt_[4];
#pragma unroll
  for (int t = 0; t < 4; ++t) {
    bC[t]  = b1g[h * 64 + t * 16 + li];
    gv[t]  = lnw[h * 64 + t * 16 + li];
    bt_[t] = lnb[h * 64 + t * 16 + li];
  }

  float tokL;
  {
    float tk = 1.f / (float)(li + 1) + tid[li];
    tokL = tk > 0.f ? tk : 0.f;
  }
  float t15 = 1.f / 16.f + tid[15];
  t15 = t15 > 0.f ? t15 : 0.f;

  // rotary tables: lane stages token l>>2, channels (l&3)*16 .. +15
  float c8[8], s8[8];
  {
    int pos = l >> 2;
#pragma unroll
    for (int pl = 0; pl < 8; ++pl) {
      int p = (l & 3) * 8 + pl;
      float inv = __expf(-((float)(2 * p) * (1.f / 64.f)) * 9.210340371976184f);
      float a = (float)pos * inv;
      c8[pl] = cosf(a);
      s8[pl] = sinf(a);
    }
  }

  // prefetch regs (q,k,v tile m=0) + per-lane lr for tokens quad*4+r
  float4 pf[3][4];
  float pflr[4];
  {
    int nn = l >> 2;
    int grow = flip ? (bN + Nseq - 1 - nn) : (bN + nn);
#pragma unroll
    for (int a = 0; a < 3; ++a) {
      const float* bse = qkv + (size_t)grow * 2304 + chan + a * 768 + (l & 3) * 16;
#pragma unroll
      for (int i = 0; i < 4; ++i) pf[a][i] = ((const float4*)bse)[i];
    }
#pragma unroll
    for (int r = 0; r < 4; ++r)
      pflr[r] = lrg[(size_t)(bN + quad * 4 + r) * NH2 + h];
  }

#pragma unroll 1
  for (int m = 0; m < NMB; ++m) {
    const int n0 = m * KB;

    // ---- stage from prefetch regs (rotary on q,k) ----
#pragma unroll
    for (int a = 0; a < 3; ++a) {
      float v16[16];
      *(float4*)(v16)      = pf[a][0]; *(float4*)(v16 + 4)  = pf[a][1];
      *(float4*)(v16 + 8)  = pf[a][2]; *(float4*)(v16 + 12) = pf[a][3];
      if (a < 2) {
#pragma unroll
        for (int pl = 0; pl < 8; ++pl) {
          float e = v16[2 * pl], o = v16[2 * pl + 1];
          v16[2 * pl]     = e * c8[pl] - o * s8[pl];
          v16[2 * pl + 1] = o * c8[pl] + e * s8[pl];
        }
      }
      float* dst = (a == 0 ? sQ : (a == 1 ? sK : sV)) + (l >> 2) * 68 + (l & 3) * 16;
#pragma unroll
      for (int i = 0; i < 4; ++i) ((f32x4*)dst)[i] = *(f32x4*)(v16 + 4 * i);
    }
    float lr4[4];
#pragma unroll
    for (int r = 0; r < 4; ++r) lr4[r] = pflr[r];
    lds_fence();                                  // S1: staging visible (only fence)

    // ---- issue global prefetch for m+1 (never force-drained in this loop) ----
    if (m < NMB - 1) {
      int nn = (m + 1) * KB + (l >> 2);
      int grow = flip ? (bN + Nseq - 1 - nn) : (bN + nn);
#pragma unroll
      for (int a = 0; a < 3; ++a) {
        const float* bse = qkv + (size_t)grow * 2304 + chan + a * 768 + (l & 3) * 16;
#pragma unroll
        for (int i = 0; i < 4; ++i) pf[a][i] = ((const float4*)bse)[i];
      }
#pragma unroll
      for (int r = 0; r < 4; ++r)
        pflr[r] = lrg[(size_t)(bN + (m + 1) * KB + quad * 4 + r) * NH2 + h];
    }

    // ---- K16 A/B frags (rows li, k-tiles kk) + C-layout K,V reads ----
    bfrag4 aQ4[4], aK4[4];
#pragma unroll
    for (int kk = 0; kk < 4; ++kk) {
      f32x4 q4 = *(const f32x4*)(&sQ[li * 68 + kk * 16 + quad * 4]);
      f32x4 k4 = *(const f32x4*)(&sK[li * 68 + kk * 16 + quad * 4]);
      aQ4[kk] = cvt4(q4[0], q4[1], q4[2], q4[3]);
      aK4[kk] = cvt4(k4[0], k4[1], k4[2], k4[3]);
    }
    float kC[4][4], vC[4][4];   // [tile][r] = tok(quad*4+r), ch(t*16+li)
#pragma unroll
    for (int t = 0; t < 4; ++t)
#pragma unroll
      for (int r = 0; r < 4; ++r) {
        int off = (quad * 4 + r) * 68 + t * 16 + li;
        kC[t][r] = sK[off]; vC[t][r] = sV[off];
      }

    // ---- MFMA: Z1 (16), xqW (16), attn^T (4) ----
    f32x4 accZ[4], accQ[4];
#pragma unroll
    for (int t = 0; t < 4; ++t) {
      accZ[t] = (f32x4){0.f, 0.f, 0.f, 0.f};
      accQ[t] = (f32x4){0.f, 0.f, 0.f, 0.f};
#pragma unroll
      for (int kk = 0; kk < 4; ++kk) {
        accZ[t] = mfma16(aK4[kk], wB[t][kk], accZ[t]);
        accQ[t] = mfma16(aQ4[kk], wB[t][kk], accQ[t]);
      }
    }
    f32x4 accAT = (f32x4){0.f, 0.f, 0.f, 0.f};
#pragma unroll
    for (int kk = 0; kk < 4; ++kk)
      accAT = mfma16(aK4[kk], aQ4[kk], accAT);    // lane: attn[li][quad*4+r]

    // ---- coef A-frag fully in-register (no LDS transpose) ----
    bfrag4 aCoef;
    {
      float cf[4];
#pragma unroll
      for (int r = 0; r < 4; ++r) {
        int j = quad * 4 + r;
        cf[r] = (j <= li) ? (-tokL * (accAT[r] + 1.f)) : 0.f;
      }
      aCoef = cvt4(cf[0], cf[1], cf[2], cf[3]);
    }

    // ---- LN-L2 backward: reductions via DPP (pure VALU) ----
    float gs[4][4];
#pragma unroll
    for (int r = 0; r < 4; ++r) {
      float zt[4], xht[4], gxht[4];
      float s1 = 0.f, s2 = 0.f;
#pragma unroll
      for (int t = 0; t < 4; ++t) {
        zt[t] = accZ[t][r] + bC[t];
        s1 += zt[t];
        s2 += zt[t] * zt[t];
      }
      s1 = rowsum16(s1);
      s2 = rowsum16(s2);
      float mu = s1 * 0.015625f;
      float var = s2 * 0.015625f - mu * mu;
      float rstd = rsqrtf(var + 1e-6f);
      float r1 = 0.f, r2 = 0.f;
#pragma unroll
      for (int t = 0; t < 4; ++t) {
        xht[t] = (zt[t] - mu) * rstd;
        float gout = gv[t] * xht[t] + bt_[t] - (vC[t][r] - kC[t][r]);
        gxht[t] = gout * gv[t];
        r1 += gxht[t];
        r2 += gxht[t] * xht[t];
      }
      r1 = rowsum16(r1);
      r2 = rowsum16(r2);
      float lrr = lr4[r];
#pragma unroll
      for (int t = 0; t < 4; ++t) {
        float gd = (64.f * gxht[t] - r1 - xht[t] * r2) * rstd * 0.015625f;
        gs[t][r] = lrr * gd;
      }
    }

    // ---- K16 frags straight from registers ----
    bfrag4 bGrad[4], aXk[4];
#pragma unroll
    for (int t = 0; t < 4; ++t) {
      bGrad[t] = cvt4(gs[t][0], gs[t][1], gs[t][2], gs[t][3]);
      aXk[t]   = cvt4(kC[t][0], kC[t][1], kC[t][2], kC[t][3]);
    }

    // ---- Z1_bar = xqW + b + coef@gradS ; LN ; output (qC read lazily) ----
    f32x4 zb[4];
#pragma unroll
    for (int t = 0; t < 4; ++t) {
      f32x4 acc = accQ[t];
#pragma unroll
      for (int r = 0; r < 4; ++r) acc[r] += bC[t];
      zb[t] = mfma16(aCoef, bGrad[t], acc);
    }
#pragma unroll
    for (int r = 0; r < 4; ++r) {
      float s1 = 0.f, s2 = 0.f;
#pragma unroll
      for (int t = 0; t < 4; ++t) { s1 += zb[t][r]; s2 += zb[t][r] * zb[t][r]; }
      s1 = rowsum16(s1);
      s2 = rowsum16(s2);
      float mu = s1 * 0.015625f;
      float var = s2 * 0.015625f - mu * mu;
      float rstd = rsqrtf(var + 1e-6f);
#pragma unroll
      for (int t = 0; t < 4; ++t) {
        float qv = sQ[(quad * 4 + r) * 68 + t * 16 + li];
        float outv = qv + gv[t] * (zb[t][r] - mu) * rstd + bt_[t];
        Zout[(size_t)(bN + n0 + quad * 4 + r) * W2D + h * 64 + t * 16 + li] = outv;
      }
    }

    // ---- G = xk^T @ gradS ; W update — PURE REGISTER (D-layout == W-frag k) --
#pragma unroll
    for (int mt = 0; mt < 4; ++mt)
#pragma unroll
      for (int t = 0; t < 4; ++t) {
        f32x4 g = mfma16(aXk[mt], bGrad[t], (f32x4){0.f, 0.f, 0.f, 0.f});
#pragma unroll
        for (int r = 0; r < 4; ++r) Wf[t][mt][r] -= t15 * g[r];
        wB[t][mt] = cvt4(Wf[t][mt][0], Wf[t][mt][1], Wf[t][mt][2], Wf[t][mt][3]);
      }
    // ---- b update (f32 gs, off critical path) ----
#pragma unroll
    for (int t = 0; t < 4; ++t) {
      float g0 = gs[t][0] + gs[t][1] + gs[t][2] + gs[t][3];
      g0 += __shfl_xor(g0, 16);
      g0 += __shfl_xor(g0, 32);
      bC[t] -= t15 * g0;
    }
    // Next-iter staging writes are ordered after this iter's LDS reads by the
    // in-order per-wave DS pipe (WAR safe, no extra fence).
  }
}

// ---------------- fused post-LN + flip-multiply -> bf16 h --------------------
__global__ __launch_bounds__(256) void postln_mult_kernel(
    const float* __restrict__ Z, const float* __restrict__ wv,
    const float* __restrict__ bb, __hip_bfloat16* __restrict__ hbuf)
{
  __shared__ float red[16];
  const int pair = blockIdx.x;          // 0..8191
  const int b = pair >> 9, n = pair & 511;
  const size_t r1 = (size_t)b * Nseq + n;
  const size_t r2 = (size_t)b * Nseq + (Nseq - 1 - n);
  const float* z1 = Z + r1 * W2D;
  const float* z2 = Z + r2 * W2D;
  const int t = threadIdx.x;

  float v1[6], v2[6];
  float s1a = 0.f, s2a = 0.f, s1b = 0.f, s2b = 0.f;
#pragma unroll
  for (int r = 0; r < 6; ++r) {
    int c = t + 256 * r;
    float a = z1[c]; v1[r] = a; s1a += a; s2a += a * a;
    float d = z2[c]; v2[r] = d; s1b += d; s2b += d * d;
  }
#pragma unroll
  for (int o = 1; o < 64; o <<= 1) {
    s1a += __shfl_xor(s1a, o); s2a += __shfl_xor(s2a, o);
    s1b += __shfl_xor(s1b, o); s2b += __shfl_xor(s2b, o);
  }
  if ((t & 63) == 0) {
    int w = t >> 6;
    red[w] = s1a; red[4 + w] = s2a; red[8 + w] = s1b; red[12 + w] = s2b;
  }
  __syncthreads();
  s1a = red[0] + red[1] + red[2] + red[3];
  s2a = red[4] + red[5] + red[6] + red[7];
  s1b = red[8] + red[9] + red[10] + red[11];
  s2b = red[12] + red[13] + red[14] + red[15];
  float mu1 = s1a * (1.f / 1536.f);
  float var1 = s2a * (1.f / 1536.f) - mu1 * mu1;
  float rstd1 = rsqrtf(var1 + 1e-6f);
  float mu2 = s1b * (1.f / 1536.f);
  float var2 = s2b * (1.f / 1536.f) - mu2 * mu2;
  float rstd2 = rsqrtf(var2 + 1e-6f);
#pragma unroll
  for (int r = 0; r < 3; ++r) {
    int c = t + 256 * r;
    float a1  = wv[c] * (v1[r] - mu1) * rstd1 + bb[c];
    float a1b = wv[c + 768] * (v1[r + 3] - mu1) * rstd1 + bb[c + 768];
    float a2  = wv[c] * (v2[r] - mu2) * rstd2 + bb[c];
    float a2b = wv[c + 768] * (v2[r + 3] - mu2) * rstd2 + bb[c + 768];
    union { __hip_bfloat16 h; short s; } u1, u2;
    u1.h = __float2bfloat16(a1 * a2b);
    u2.h = __float2bfloat16(a2 * a1b);
    ((short*)hbuf)[r1 * Cdim + c] = u1.s;
    ((short*)hbuf)[r2 * Cdim + c] = u2.s;
  }
}

// ---------------- launch -----------------------------------------------------
extern "C" void kernel_launch(void* const* d_in, const int* in_sizes, int n_in,
                              void* d_out, int out_size, void* d_ws, size_t ws_size,
                              hipStream_t stream)
{
  const float* x         = (const float*)d_in[0];
  const float* qkv_w     = (const float*)d_in[1];
  const float* proj_w    = (const float*)d_in[2];
  const float* proj_b    = (const float*)d_in[3];
  const float* W1        = (const float*)d_in[4];
  const float* b1        = (const float*)d_in[5];
  const float* ttt_ln_w  = (const float*)d_in[6];
  const float* ttt_ln_b  = (const float*)d_in[7];
  const float* post_ln_w = (const float*)d_in[8];
  const float* post_ln_b = (const float*)d_in[9];
  const float* lr_w      = (const float*)d_in[10];
  const float* lr_b      = (const float*)d_in[11];
  const float* tid       = (const float*)d_in[12];
  float* out = (float*)d_out;
  float* ws  = (float*)d_ws;

  float* qkv   = ws;                                   // [0, 37748736)
  float* lrbuf = ws + 37748736;                        // [.., 38141952)
  float* Zbuf  = ws + 38141952;                        // [.., 63307776)
  __hip_bfloat16* xbf    = (__hip_bfloat16*)(ws + 38141952);  // dead before Zbuf use
  __hip_bfloat16* wqkv_t = (__hip_bfloat16*)(ws + 44433408);  // dead before Zbuf use
  __hip_bfloat16* hbf    = (__hip_bfloat16*)(ws + 25165824);  // in dead qkv region
  __hip_bfloat16* wproj_t= (__hip_bfloat16*)(ws + 37748736);  // in dead lrbuf region

  const int Mrows = Bq * Nseq;             // 16384

  {
    dim3 g(Cdim / 64, 3 * Cdim / 64);
    transpose_cast_kernel<<<g, 256, 0, stream>>>(qkv_w, wqkv_t, Cdim, 3 * Cdim);
  }
  lrcast_kernel<<<Mrows / 2, 64, 0, stream>>>(x, lr_w, lr_b, lrbuf, xbf);
  {
    int gx = 3 * Cdim / 128;               // 18
    int nwg = gx * (Mrows / 128);          // 2304 (% 8 == 0)
    gemm_bf16_kernel<<<nwg, 256, 0, stream>>>(xbf, wqkv_t, nullptr, qkv, Mrows, Cdim, 3 * Cdim, gx);
  }

  ttt_scan_kernel<<<Bq * NH2, 64, 0, stream>>>(qkv, lrbuf, W1, b1, ttt_ln_w, ttt_ln_b, tid, Zbuf);

  postln_mult_kernel<<<Bq * Nseq / 2, 256, 0, stream>>>(Zbuf, post_ln_w, post_ln_b, hbf);
  {
    dim3 g(Cdim / 64, Cdim / 64);
    transpose_cast_kernel<<<g, 256, 0, stream>>>(proj_w, wproj_t, Cdim, Cdim);
  }
  {
    int gx = Cdim / 128;                   // 6
    int nwg = gx * (Mrows / 128);          // 768 (% 8 == 0)
    gemm_bf16_kernel<<<nwg, 256, 0, stream>>>(hbf, wproj_t, proj_b, out, Mrows, Cdim, Cdim, gx);
  }
}